// Round 15
// baseline (64.448 us; speedup 1.0000x reference)
//
#include <hip/hip_runtime.h>

#define LRELU_SLOPE 0.2f

// ---------------- workspace layout (float offsets) ----------------
#define OFF_UV0  0u
#define OFF_U1   512u
#define OFF_V1   1024u
#define OFF_P    1536u
#define OFF_PP   2048u
#define OFF_Q    4096u
#define OFF_R    69632u
#define OFF_Y1   135168u
#define OFF_Y0   2756608u

__device__ __forceinline__ float dot4(float4 a, float4 b) {
    return a.x * b.x + a.y * b.y + a.z * b.z + a.w * b.w;
}

template<int CTRL>
__device__ __forceinline__ float dppmov(float x) {
    return __int_as_float(__builtin_amdgcn_update_dpp(
        0, __float_as_int(x), CTRL, 0xf, 0xf, true));
}
__device__ __forceinline__ float sum16(float x) {
    x += dppmov<0xB1>(x);
    x += dppmov<0x4E>(x);
    x += dppmov<0x141>(x);
    x += dppmov<0x140>(x);
    return x;
}
__device__ __forceinline__ float sum32(float x) {
    x = sum16(x);
    return x + __shfl_xor(x, 16);
}
__device__ __forceinline__ float sum64(float x) {
    float y = sum32(x);
    return y + __shfl_xor(y, 32);
}
__device__ __forceinline__ float lrelu(float x) {
    return (x >= 0.f) ? x : LRELU_SLOPE * x;
}

// global -> LDS direct copy, 16 B/lane. LDS dest is WAVE-UNIFORM base;
// HW scatters lane i to base + i*16 bytes. Device-pass only (host never sees it).
__device__ __forceinline__ void glds16(const float* gsrc, float* ldst) {
#if defined(__HIP_DEVICE_COMPILE__)
    __builtin_amdgcn_global_load_lds(
        (const __attribute__((address_space(1))) unsigned int*)gsrc,
        (__attribute__((address_space(3))) unsigned int*)ldst,
        16, 0, 0);
#endif
}

// ============ prepA: uv0, u1/v1, Q = W1 @ fcW-block (unchanged) ============
__global__ __launch_bounds__(256)
void prepA_kernel(const float* __restrict__ W0, const float* __restrict__ as0,
                  const float* __restrict__ an0,
                  const float* __restrict__ W1, const float* __restrict__ as1,
                  const float* __restrict__ an1,
                  const float* __restrict__ fcW, float* __restrict__ ws) {
    __shared__ float s[16 * 129];
    const int b = blockIdx.x;
    const int t = threadIdx.x;
    if (b < 192) {
        const int wid = b * 4 + (t >> 6);
        const int lane = t & 63;
        const float *wrow, *as, *an;
        if (wid < 256) {
            wrow = W0 + (size_t)wid * 128;
            int h = wid >> 7;
            as = as0 + h * 128; an = an0 + h * 128;
        } else {
            int g = wid - 256;
            wrow = W1 + (size_t)g * 128;
            int h = g >> 8;
            as = as1 + h * 128; an = an1 + h * 128;
        }
        float2 w = *(const float2*)(wrow + 2 * lane);
        float2 sv = *(const float2*)(as + 2 * lane);
        float2 nv = *(const float2*)(an + 2 * lane);
        float au = sum64(w.x * sv.x + w.y * sv.y);
        float av = sum64(w.x * nv.x + w.y * nv.y);
        if (lane == 0) {
            if (wid < 256) { ws[OFF_UV0 + wid] = au; ws[OFF_UV0 + 256 + wid] = av; }
            else { int g = wid - 256; ws[OFF_U1 + g] = au; ws[OFF_V1 + g] = av; }
        }
    } else {
        const int idx = b - 192;
        const int h = idx >> 4, g0 = (idx & 15) * 16;
        const float* Wh = W1 + (size_t)h * 32768;
        for (int ii = t * 4; ii < 16 * 128; ii += 1024) {
            int i = ii >> 7, d = ii & 127;
            float4 g4 = *(const float4*)(Wh + (size_t)(g0 + i) * 128 + d);
            s[i * 129 + d + 0] = g4.x;
            s[i * 129 + d + 1] = g4.y;
            s[i * 129 + d + 2] = g4.z;
            s[i * 129 + d + 3] = g4.w;
        }
        __syncthreads();
        const int dg = t & 31, rg = t >> 5;
        float4 acc[2];
        acc[0] = make_float4(0.f, 0.f, 0.f, 0.f);
        acc[1] = make_float4(0.f, 0.f, 0.f, 0.f);
        const float* fp = fcW + (size_t)h * 16384 + 4 * dg;
        #pragma unroll 4
        for (int d2 = 0; d2 < 128; ++d2) {
            float4 f4 = *(const float4*)(fp + (size_t)d2 * 128);
            #pragma unroll
            for (int j = 0; j < 2; ++j) {
                float x = s[(rg * 2 + j) * 129 + d2];
                acc[j].x += x * f4.x; acc[j].y += x * f4.y;
                acc[j].z += x * f4.z; acc[j].w += x * f4.w;
            }
        }
        float* Qp = ws + OFF_Q + (size_t)h * 32768;
        #pragma unroll
        for (int j = 0; j < 2; ++j)
            *(float4*)(Qp + (size_t)(g0 + rg * 2 + j) * 128 + 4 * dg) = acc[j];
    }
}

// online-softmax updates
__device__ __forceinline__ void upd2(float& m, float& s, float4& A,
                                     float ea, float eb,
                                     const float4& xa, const float4& xb) {
    float mn = fmaxf(m, fmaxf(ea, eb));
    float sc = __expf(m - mn);
    float pa = __expf(ea - mn);
    float pb = __expf(eb - mn);
    s = s * sc + pa + pb;
    A.x = A.x * sc + pa * xa.x + pb * xb.x;
    A.y = A.y * sc + pa * xa.y + pb * xb.y;
    A.z = A.z * sc + pa * xa.z + pb * xb.z;
    A.w = A.w * sc + pa * xa.w + pb * xb.w;
    m = mn;
}
__device__ __forceinline__ void upd1(float& m, float& s, float4& A,
                                     float ea, const float4& xa) {
    float mn = fmaxf(m, ea);
    float sc = __expf(m - mn);
    float pa = __expf(ea - mn);
    s = s * sc + pa;
    A.x = A.x * sc + pa * xa.x;
    A.y = A.y * sc + pa * xa.y;
    A.z = A.z * sc + pa * xa.z;
    A.w = A.w * sc + pa * xa.w;
    m = mn;
}

// ============ big7: attn25 via global_load_lds burst staging (no barriers) ============
// blocks: [0,2560) attn25 (4 tgt/blk, wave-per-target, 52KB LDS)
//         [2560,2688) attn10 (reg path) | [2688,2816) P/P' | [2816,2848) R
__global__ __launch_bounds__(256)
void big7_kernel(const float* __restrict__ h0, const float* __restrict__ h1,
                 const float* __restrict__ h2, const float* __restrict__ W0,
                 float* __restrict__ ws) {
    __shared__ float xl[4 * 3328];          // 52 KB: 4 targets x (25 rows + self)
    const int b = blockIdx.x;
    const int t = threadIdx.x;
    const float* uv0 = ws + OFF_UV0;

    if (b < 2560) {
        const int w = t >> 6;
        const int lane = t & 63;
        const int half = lane >> 5;
        const int fl = lane & 31;
        const int m = b * 4 + w;
        float* tb = xl + w * 3328;

        // ---- burst stage: 13 x 1KB global->LDS, wave-private, no VGPR round-trip
        {
            const float* src = h2 + (size_t)m * 3200;
            #pragma unroll
            for (int i = 0; i < 12; ++i)
                glds16(src + i * 256 + lane * 4, tb + i * 256);
            // inst 12: lanes 0-31 = row 24; lanes 32-63 = self row from h1
            const float* g12 = (lane < 32) ? (src + 3072 + lane * 4)
                                           : (h1 + (size_t)m * 128 + (lane - 32) * 4);
            glds16(g12, tb + 3072);
            asm volatile("s_waitcnt vmcnt(0)" ::: "memory");
        }

        // ---- compute from LDS: half h owns rows {2i+h}
        const float4 u0 = *(const float4*)(uv0 + 0 + 4 * fl);
        const float4 u1 = *(const float4*)(uv0 + 128 + 4 * fl);
        const float4 v0 = *(const float4*)(uv0 + 256 + 4 * fl);
        const float4 v1 = *(const float4*)(uv0 + 384 + 4 * fl);
        float es0, es1;
        {
            float4 xs = *(const float4*)(tb + 3200 + 4 * fl);   // self (floats 3200..3327)
            es0 = sum32(dot4(xs, u0));
            es1 = sum32(dot4(xs, u1));
        }
        float m0 = -1e30f, m1 = -1e30f, s0 = 0.f, s1 = 0.f;
        float4 A0 = make_float4(0.f, 0.f, 0.f, 0.f);
        float4 A1 = make_float4(0.f, 0.f, 0.f, 0.f);
        #pragma unroll
        for (int i = 0; i < 13; ++i) {
            int row = 2 * i + half;
            const bool dead = (row > 24);   // half1 @ i=12
            if (dead) row = 24;
            float4 x = *(const float4*)(tb + row * 128 + 4 * fl);
            float e0 = lrelu(es0 + sum32(dot4(x, v0)));
            float e1 = lrelu(es1 + sum32(dot4(x, v1)));
            if (dead) { e0 = -1e30f; e1 = -1e30f; }
            upd1(m0, s0, A0, e0, x);
            upd1(m1, s1, A1, e1, x);
        }
        // cross-half merge
        float g0 = fmaxf(m0, __shfl_xor(m0, 32));
        float g1 = fmaxf(m1, __shfl_xor(m1, 32));
        float c0 = __expf(m0 - g0), c1 = __expf(m1 - g1);
        s0 *= c0; s1 *= c1;
        A0.x *= c0; A0.y *= c0; A0.z *= c0; A0.w *= c0;
        A1.x *= c1; A1.y *= c1; A1.z *= c1; A1.w *= c1;
        s0 += __shfl_xor(s0, 32); s1 += __shfl_xor(s1, 32);
        A0.x += __shfl_xor(A0.x, 32); A0.y += __shfl_xor(A0.y, 32);
        A0.z += __shfl_xor(A0.z, 32); A0.w += __shfl_xor(A0.w, 32);
        A1.x += __shfl_xor(A1.x, 32); A1.y += __shfl_xor(A1.y, 32);
        A1.z += __shfl_xor(A1.z, 32); A1.w += __shfl_xor(A1.w, 32);
        const float inv = 1.f / (half ? s1 : s0);
        const float4 S = half ? A1 : A0;
        float4 o;
        o.x = S.x * inv; o.y = S.y * inv; o.z = S.z * inv; o.w = S.w * inv;
        *(float4*)(ws + OFF_Y1 + (size_t)m * 256 + half * 128 + 4 * fl) = o;
    } else if (b < 2688) {
        // ---- attn10: register path with depth-4 prefetch (R13)
        const int lane = t & 63;
        const int sub = lane >> 5;
        const int fl = lane & 31;
        const int m = ((b - 2560) * 4 + (t >> 6)) * 2 + sub;
        const float* xnp = h1 + (size_t)m * 1280;
        float es0, es1;
        {
            const float4 xs = *(const float4*)(h0 + (size_t)m * 128 + 4 * fl);
            const float4 u0 = *(const float4*)(uv0 + 0 + 4 * fl);
            const float4 u1 = *(const float4*)(uv0 + 128 + 4 * fl);
            es0 = sum32(dot4(xs, u0));
            es1 = sum32(dot4(xs, u1));
        }
        const float4 v0 = *(const float4*)(uv0 + 256 + 4 * fl);
        const float4 v1 = *(const float4*)(uv0 + 384 + 4 * fl);

        float4 xa = *(const float4*)(xnp + 4 * fl);
        float4 xb = *(const float4*)(xnp + 128 + 4 * fl);
        float4 xc = *(const float4*)(xnp + 256 + 4 * fl);
        float4 xd = *(const float4*)(xnp + 384 + 4 * fl);
        float m0 = -1e30f, m1 = -1e30f, s0 = 0.f, s1 = 0.f;
        float4 A0 = make_float4(0.f, 0.f, 0.f, 0.f);
        float4 A1 = make_float4(0.f, 0.f, 0.f, 0.f);
        #pragma unroll
        for (int c = 0; c < 5; ++c) {
            float4 na, nb;
            if (c < 3) {
                na = *(const float4*)(xnp + (size_t)(2 * c + 4) * 128 + 4 * fl);
                nb = *(const float4*)(xnp + (size_t)(2 * c + 5) * 128 + 4 * fl);
            } else {
                na = xc; nb = xd;
            }
            float ea0 = lrelu(es0 + sum32(dot4(xa, v0)));
            float ea1 = lrelu(es1 + sum32(dot4(xa, v1)));
            float eb0 = lrelu(es0 + sum32(dot4(xb, v0)));
            float eb1 = lrelu(es1 + sum32(dot4(xb, v1)));
            upd2(m0, s0, A0, ea0, eb0, xa, xb);
            upd2(m1, s1, A1, ea1, eb1, xa, xb);
            xa = xc; xb = xd; xc = na; xd = nb;
        }
        const float i0 = 1.f / s0, i1 = 1.f / s1;
        float4 o0, o1;
        o0.x = A0.x * i0; o0.y = A0.y * i0; o0.z = A0.z * i0; o0.w = A0.w * i0;
        o1.x = A1.x * i1; o1.y = A1.y * i1; o1.z = A1.z * i1; o1.w = A1.w * i1;
        *(float4*)(ws + OFF_Y0 + (size_t)m * 256 + 4 * fl) = o0;
        *(float4*)(ws + OFF_Y0 + (size_t)m * 256 + 128 + 4 * fl) = o1;
    } else if (b < 2816) {
        const int wid = (b - 2688) * 4 + (t >> 6);
        const int lane = t & 63;
        const int h = wid >> 8, rest = wid & 255;
        const int h0i = rest >> 7;
        const float* wrow = W0 + (size_t)rest * 128;
        float2 w2 = *(const float2*)(wrow + 2 * lane);
        float2 su = *(const float2*)(ws + OFF_U1 + h * 256 + h0i * 128 + 2 * lane);
        float2 sv = *(const float2*)(ws + OFF_V1 + h * 256 + h0i * 128 + 2 * lane);
        float pu = sum64(w2.x * su.x + w2.y * su.y);
        float pv = sum64(w2.x * sv.x + w2.y * sv.y);
        if (lane == 0) { ws[OFF_PP + wid] = pu; ws[OFF_P + wid] = pv; }
    } else {
        // R tiles: 32 blocks of 16-row tiles (reuse xl as scratch)
        float* smem = xl;
        const int idx = b - 2816;
        const int h = idx >> 4;
        const int h0i = (idx >> 3) & 1;
        const int f0 = (idx & 7) * 16;
        const float* W0h = W0 + (size_t)h0i * 16384;
        for (int ii = t * 4; ii < 16 * 128; ii += 1024) {
            int i = ii >> 7, d = ii & 127;
            float4 g4 = *(const float4*)(W0h + (size_t)(f0 + i) * 128 + d);
            smem[i * 129 + d + 0] = g4.x;
            smem[i * 129 + d + 1] = g4.y;
            smem[i * 129 + d + 2] = g4.z;
            smem[i * 129 + d + 3] = g4.w;
        }
        __syncthreads();
        const int dg = t & 31, rg = t >> 5;
        float4 acc[2];
        acc[0] = make_float4(0.f, 0.f, 0.f, 0.f);
        acc[1] = make_float4(0.f, 0.f, 0.f, 0.f);
        const float* Qp = ws + OFF_Q + (size_t)h * 32768 + (size_t)h0i * 16384 + 4 * dg;
        #pragma unroll 4
        for (int d = 0; d < 128; ++d) {
            float4 q4 = *(const float4*)(Qp + (size_t)d * 128);
            #pragma unroll
            for (int j = 0; j < 2; ++j) {
                float x = smem[(rg * 2 + j) * 129 + d];
                acc[j].x += x * q4.x; acc[j].y += x * q4.y;
                acc[j].z += x * q4.z; acc[j].w += x * q4.w;
            }
        }
        float* Rp = ws + OFF_R + (size_t)h * 32768 + (size_t)h0i * 16384;
        #pragma unroll
        for (int j = 0; j < 2; ++j)
            *(float4*)(Rp + (size_t)(f0 + rg * 2 + j) * 128 + 4 * dg) = acc[j];
    }
}

// ============ FINAL: 512 threads/block (unchanged R10) ============
__global__ __launch_bounds__(512)
void final_kernel(const float* __restrict__ ws, float* __restrict__ out) {
    __shared__ float xn[22 * 256];
    __shared__ float yb[1024];
    __shared__ float pr[8][2][128];
    __shared__ float en[2][11][2];
    __shared__ float al[2][10][2];
    const int t = threadIdx.x;
    const int m0 = blockIdx.x * 2;
    const int rlane = t & 63;
    const int rg = t >> 6;
    const float* P  = ws + OFF_P;
    const float* Pp = ws + OFF_PP;
    const float* Y1 = ws + OFF_Y1;
    const float* Y0 = ws + OFF_Y0;
    const float4 su0 = *(const float4*)(Pp + 0 + 4 * rlane);
    const float4 su1 = *(const float4*)(Pp + 256 + 4 * rlane);
    const float4 nv0 = *(const float4*)(P + 0 + 4 * rlane);
    const float4 nv1 = *(const float4*)(P + 256 + 4 * rlane);
    float4 g[3];
    #pragma unroll
    for (int i = 0; i < 3; ++i) {
        int rho = rg + 8 * i;
        if (rho < 22) {
            int r = rho / 11, k = rho % 11;
            int m = m0 + r;
            const float* src = (k < 10) ? (Y1 + ((size_t)m * 10 + k) * 256)
                                        : (Y0 + (size_t)m * 256);
            g[i] = *(const float4*)(src + 4 * rlane);
        }
    }
    #pragma unroll
    for (int i = 0; i < 3; ++i) {
        int rho = rg + 8 * i;
        if (rho < 22) {
            int r = rho / 11, k = rho % 11;
            *(float4*)(&xn[rho * 256 + 4 * rlane]) = g[i];
            float p0 = sum64(dot4(g[i], (k < 10) ? nv0 : su0));
            float p1 = sum64(dot4(g[i], (k < 10) ? nv1 : su1));
            if (rlane == 0) { en[r][k][0] = p0; en[r][k][1] = p1; }
        }
    }
    __syncthreads();
    if (t < 128) {
        int r = t >> 6, h = (t >> 5) & 1, k = t & 31;
        float e = -1e30f;
        if (k < 10) {
            float z = en[r][10][h] + en[r][k][h];
            e = (z >= 0.f) ? z : LRELU_SLOPE * z;
        }
        float mx = e;
        #pragma unroll
        for (int off = 16; off > 0; off >>= 1) mx = fmaxf(mx, __shfl_xor(mx, off));
        float ex = (k < 10) ? __expf(e - mx) : 0.f;
        float sm = ex;
        #pragma unroll
        for (int off = 16; off > 0; off >>= 1) sm += __shfl_xor(sm, off);
        if (k < 10) al[r][k][h] = ex / sm;
    }
    __syncthreads();
    #pragma unroll
    for (int i = 0; i < 2; ++i) {
        int c = t + 512 * i;
        int r = c >> 9, rem = c & 511, h = rem >> 8, f = rem & 255;
        float acc = 0.f;
        #pragma unroll
        for (int k = 0; k < 10; ++k) acc += al[r][k][h] * xn[(r * 11 + k) * 256 + f];
        yb[c] = acc;
    }
    __syncthreads();
    {
        const int seg = t >> 6;
        const int op = (t & 63) * 2;
        const float* Rv = ws + OFF_R + (size_t)seg * 64 * 128 + op;
        const float* y0p = yb + seg * 64;
        const float* y1p = yb + 512 + seg * 64;
        float2 a0 = make_float2(0.f, 0.f), a1 = make_float2(0.f, 0.f);
        #pragma unroll 8
        for (int gi = 0; gi < 64; ++gi) {
            float2 rv = *(const float2*)(Rv + (size_t)gi * 128);
            float ya = y0p[gi], yc = y1p[gi];
            a0.x += ya * rv.x; a0.y += ya * rv.y;
            a1.x += yc * rv.x; a1.y += yc * rv.y;
        }
        pr[seg][0][op] = a0.x; pr[seg][0][op + 1] = a0.y;
        pr[seg][1][op] = a1.x; pr[seg][1][op + 1] = a1.y;
    }
    __syncthreads();
    if (t < 256) {
        const int r = t >> 7, o = t & 127;
        float acc = 0.f;
        #pragma unroll
        for (int s = 0; s < 8; ++s) acc += pr[s][r][o];
        out[(size_t)(m0 + r) * 128 + o] = acc;
    }
}

extern "C" void kernel_launch(void* const* d_in, const int* in_sizes, int n_in,
                              void* d_out, int out_size, void* d_ws, size_t ws_size,
                              hipStream_t stream) {
    const float* h0  = (const float*)d_in[0];
    const float* h1  = (const float*)d_in[1];
    const float* h2  = (const float*)d_in[2];
    const float* W0  = (const float*)d_in[3];
    const float* as0 = (const float*)d_in[4];
    const float* an0 = (const float*)d_in[5];
    const float* W1  = (const float*)d_in[6];
    const float* as1 = (const float*)d_in[7];
    const float* an1 = (const float*)d_in[8];
    const float* fcW = (const float*)d_in[9];
    float* outp = (float*)d_out;
    float* ws = (float*)d_ws;

    hipLaunchKernelGGL(prepA_kernel, dim3(224), dim3(256), 0, stream,
                       W0, as0, an0, W1, as1, an1, fcW, ws);
    hipLaunchKernelGGL(big7_kernel, dim3(2848), dim3(256), 0, stream,
                       h0, h1, h2, W0, ws);
    hipLaunchKernelGGL(final_kernel, dim3(512), dim3(512), 0, stream,
                       ws, outp);
}

// Round 16
// 59.104 us; speedup vs baseline: 1.0904x; 1.0904x over previous
//
#include <hip/hip_runtime.h>

#define LRELU_SLOPE 0.2f

// ---------------- workspace layout (float offsets) ----------------
#define OFF_UV0  0u
#define OFF_U1   512u
#define OFF_V1   1024u
#define OFF_P    1536u
#define OFF_PP   2048u
#define OFF_Q    4096u
#define OFF_R    69632u
#define OFF_Y1   135168u
#define OFF_Y0   2756608u

__device__ __forceinline__ float dot4(float4 a, float4 b) {
    return a.x * b.x + a.y * b.y + a.z * b.z + a.w * b.w;
}

template<int CTRL>
__device__ __forceinline__ float dppmov(float x) {
    return __int_as_float(__builtin_amdgcn_update_dpp(
        0, __float_as_int(x), CTRL, 0xf, 0xf, true));
}
__device__ __forceinline__ float sum16(float x) {
    x += dppmov<0xB1>(x);
    x += dppmov<0x4E>(x);
    x += dppmov<0x141>(x);
    x += dppmov<0x140>(x);
    return x;
}
__device__ __forceinline__ float sum32(float x) {
    x = sum16(x);
    return x + __shfl_xor(x, 16);
}
__device__ __forceinline__ float sum64(float x) {
    float y = sum32(x);
    return y + __shfl_xor(y, 32);
}
__device__ __forceinline__ float lrelu(float x) {
    return (x >= 0.f) ? x : LRELU_SLOPE * x;
}

// ============ prepA: uv0, u1/v1, Q = W1 @ fcW-block ============
__global__ __launch_bounds__(256)
void prepA_kernel(const float* __restrict__ W0, const float* __restrict__ as0,
                  const float* __restrict__ an0,
                  const float* __restrict__ W1, const float* __restrict__ as1,
                  const float* __restrict__ an1,
                  const float* __restrict__ fcW, float* __restrict__ ws) {
    __shared__ float s[16 * 129];
    const int b = blockIdx.x;
    const int t = threadIdx.x;
    if (b < 192) {
        const int wid = b * 4 + (t >> 6);
        const int lane = t & 63;
        const float *wrow, *as, *an;
        if (wid < 256) {
            wrow = W0 + (size_t)wid * 128;
            int h = wid >> 7;
            as = as0 + h * 128; an = an0 + h * 128;
        } else {
            int g = wid - 256;
            wrow = W1 + (size_t)g * 128;
            int h = g >> 8;
            as = as1 + h * 128; an = an1 + h * 128;
        }
        float2 w = *(const float2*)(wrow + 2 * lane);
        float2 sv = *(const float2*)(as + 2 * lane);
        float2 nv = *(const float2*)(an + 2 * lane);
        float au = sum64(w.x * sv.x + w.y * sv.y);
        float av = sum64(w.x * nv.x + w.y * nv.y);
        if (lane == 0) {
            if (wid < 256) { ws[OFF_UV0 + wid] = au; ws[OFF_UV0 + 256 + wid] = av; }
            else { int g = wid - 256; ws[OFF_U1 + g] = au; ws[OFF_V1 + g] = av; }
        }
    } else {
        const int idx = b - 192;
        const int h = idx >> 4, g0 = (idx & 15) * 16;
        const float* Wh = W1 + (size_t)h * 32768;
        for (int ii = t * 4; ii < 16 * 128; ii += 1024) {
            int i = ii >> 7, d = ii & 127;
            float4 g4 = *(const float4*)(Wh + (size_t)(g0 + i) * 128 + d);
            s[i * 129 + d + 0] = g4.x;
            s[i * 129 + d + 1] = g4.y;
            s[i * 129 + d + 2] = g4.z;
            s[i * 129 + d + 3] = g4.w;
        }
        __syncthreads();
        const int dg = t & 31, rg = t >> 5;
        float4 acc[2];
        acc[0] = make_float4(0.f, 0.f, 0.f, 0.f);
        acc[1] = make_float4(0.f, 0.f, 0.f, 0.f);
        const float* fp = fcW + (size_t)h * 16384 + 4 * dg;
        #pragma unroll 4
        for (int d2 = 0; d2 < 128; ++d2) {
            float4 f4 = *(const float4*)(fp + (size_t)d2 * 128);
            #pragma unroll
            for (int j = 0; j < 2; ++j) {
                float x = s[(rg * 2 + j) * 129 + d2];
                acc[j].x += x * f4.x; acc[j].y += x * f4.y;
                acc[j].z += x * f4.z; acc[j].w += x * f4.w;
            }
        }
        float* Qp = ws + OFF_Q + (size_t)h * 32768;
        #pragma unroll
        for (int j = 0; j < 2; ++j)
            *(float4*)(Qp + (size_t)(g0 + rg * 2 + j) * 128 + 4 * dg) = acc[j];
    }
}

// online-softmax updates
__device__ __forceinline__ void upd2(float& m, float& s, float4& A,
                                     float ea, float eb,
                                     const float4& xa, const float4& xb) {
    float mn = fmaxf(m, fmaxf(ea, eb));
    float sc = __expf(m - mn);
    float pa = __expf(ea - mn);
    float pb = __expf(eb - mn);
    s = s * sc + pa + pb;
    A.x = A.x * sc + pa * xa.x + pb * xb.x;
    A.y = A.y * sc + pa * xa.y + pb * xb.y;
    A.z = A.z * sc + pa * xa.z + pb * xb.z;
    A.w = A.w * sc + pa * xa.w + pb * xb.w;
    m = mn;
}
__device__ __forceinline__ void upd1(float& m, float& s, float4& A,
                                     float ea, const float4& xa) {
    float mn = fmaxf(m, ea);
    float sc = __expf(m - mn);
    float pa = __expf(ea - mn);
    s = s * sc + pa;
    A.x = A.x * sc + pa * xa.x;
    A.y = A.y * sc + pa * xa.y;
    A.z = A.z * sc + pa * xa.z;
    A.w = A.w * sc + pa * xa.w;
    m = mn;
}

// ============ big6: 2 targets/wave, DEPTH-4 row prefetch, natural VGPR ============
// blocks: [0,1280) attn25 | [1280,1408) attn10 | [1408,1536) P/P' | [1536,1568) R
__global__ __launch_bounds__(256)
void big6_kernel(const float* __restrict__ h0, const float* __restrict__ h1,
                 const float* __restrict__ h2, const float* __restrict__ W0,
                 float* __restrict__ ws) {
    const int b = blockIdx.x;
    const int t = threadIdx.x;
    const float* uv0 = ws + OFF_UV0;

    if (b < 1280) {
        const int lane = t & 63;
        const int sub = lane >> 5;
        const int fl = lane & 31;
        const int m = (b * 4 + (t >> 6)) * 2 + sub;
        const float* xnp = h2 + (size_t)m * 3200;
        float es0, es1;
        {
            const float4 xs = *(const float4*)(h1 + (size_t)m * 128 + 4 * fl);
            const float4 u0 = *(const float4*)(uv0 + 0 + 4 * fl);
            const float4 u1 = *(const float4*)(uv0 + 128 + 4 * fl);
            es0 = sum32(dot4(xs, u0));
            es1 = sum32(dot4(xs, u1));
        }
        const float4 v0 = *(const float4*)(uv0 + 256 + 4 * fl);
        const float4 v1 = *(const float4*)(uv0 + 384 + 4 * fl);

        // depth-4 prefetch: (xa,xb)=rows(0,1) current; (xc,xd)=rows(2,3) ahead
        float4 xa = *(const float4*)(xnp + 4 * fl);
        float4 xb = *(const float4*)(xnp + 128 + 4 * fl);
        float4 xc = *(const float4*)(xnp + 256 + 4 * fl);
        float4 xd = *(const float4*)(xnp + 384 + 4 * fl);
        float m0 = -1e30f, m1 = -1e30f, s0 = 0.f, s1 = 0.f;
        float4 A0 = make_float4(0.f, 0.f, 0.f, 0.f);
        float4 A1 = make_float4(0.f, 0.f, 0.f, 0.f);
        #pragma unroll
        for (int c = 0; c < 12; ++c) {      // pair c = rows (2c, 2c+1)
            float4 na, nb;
            if (c < 10) {
                na = *(const float4*)(xnp + (size_t)(2 * c + 4) * 128 + 4 * fl);
                nb = *(const float4*)(xnp + (size_t)(2 * c + 5) * 128 + 4 * fl);
            } else if (c == 10) {
                na = *(const float4*)(xnp + (size_t)24 * 128 + 4 * fl);
                nb = na;
            } else {
                na = xc; nb = xd;           // placeholders (unused)
            }
            float ea0 = lrelu(es0 + sum32(dot4(xa, v0)));
            float ea1 = lrelu(es1 + sum32(dot4(xa, v1)));
            float eb0 = lrelu(es0 + sum32(dot4(xb, v0)));
            float eb1 = lrelu(es1 + sum32(dot4(xb, v1)));
            upd2(m0, s0, A0, ea0, eb0, xa, xb);
            upd2(m1, s1, A1, ea1, eb1, xa, xb);
            xa = xc; xb = xd; xc = na; xd = nb;
        }
        {   // tail: row 24 (now in xa; valid for both halves)
            float e0 = lrelu(es0 + sum32(dot4(xa, v0)));
            float e1 = lrelu(es1 + sum32(dot4(xa, v1)));
            upd1(m0, s0, A0, e0, xa);
            upd1(m1, s1, A1, e1, xa);
        }
        const float i0 = 1.f / s0, i1 = 1.f / s1;
        float4 o0, o1;
        o0.x = A0.x * i0; o0.y = A0.y * i0; o0.z = A0.z * i0; o0.w = A0.w * i0;
        o1.x = A1.x * i1; o1.y = A1.y * i1; o1.z = A1.z * i1; o1.w = A1.w * i1;
        *(float4*)(ws + OFF_Y1 + (size_t)m * 256 + 4 * fl) = o0;
        *(float4*)(ws + OFF_Y1 + (size_t)m * 256 + 128 + 4 * fl) = o1;
    } else if (b < 1408) {
        const int lane = t & 63;
        const int sub = lane >> 5;
        const int fl = lane & 31;
        const int m = ((b - 1280) * 4 + (t >> 6)) * 2 + sub;
        const float* xnp = h1 + (size_t)m * 1280;
        float es0, es1;
        {
            const float4 xs = *(const float4*)(h0 + (size_t)m * 128 + 4 * fl);
            const float4 u0 = *(const float4*)(uv0 + 0 + 4 * fl);
            const float4 u1 = *(const float4*)(uv0 + 128 + 4 * fl);
            es0 = sum32(dot4(xs, u0));
            es1 = sum32(dot4(xs, u1));
        }
        const float4 v0 = *(const float4*)(uv0 + 256 + 4 * fl);
        const float4 v1 = *(const float4*)(uv0 + 384 + 4 * fl);

        float4 xa = *(const float4*)(xnp + 4 * fl);
        float4 xb = *(const float4*)(xnp + 128 + 4 * fl);
        float4 xc = *(const float4*)(xnp + 256 + 4 * fl);
        float4 xd = *(const float4*)(xnp + 384 + 4 * fl);
        float m0 = -1e30f, m1 = -1e30f, s0 = 0.f, s1 = 0.f;
        float4 A0 = make_float4(0.f, 0.f, 0.f, 0.f);
        float4 A1 = make_float4(0.f, 0.f, 0.f, 0.f);
        #pragma unroll
        for (int c = 0; c < 5; ++c) {       // pairs (0,1)..(8,9)
            float4 na, nb;
            if (c < 3) {
                na = *(const float4*)(xnp + (size_t)(2 * c + 4) * 128 + 4 * fl);
                nb = *(const float4*)(xnp + (size_t)(2 * c + 5) * 128 + 4 * fl);
            } else {
                na = xc; nb = xd;
            }
            float ea0 = lrelu(es0 + sum32(dot4(xa, v0)));
            float ea1 = lrelu(es1 + sum32(dot4(xa, v1)));
            float eb0 = lrelu(es0 + sum32(dot4(xb, v0)));
            float eb1 = lrelu(es1 + sum32(dot4(xb, v1)));
            upd2(m0, s0, A0, ea0, eb0, xa, xb);
            upd2(m1, s1, A1, ea1, eb1, xa, xb);
            xa = xc; xb = xd; xc = na; xd = nb;
        }
        const float i0 = 1.f / s0, i1 = 1.f / s1;
        float4 o0, o1;
        o0.x = A0.x * i0; o0.y = A0.y * i0; o0.z = A0.z * i0; o0.w = A0.w * i0;
        o1.x = A1.x * i1; o1.y = A1.y * i1; o1.z = A1.z * i1; o1.w = A1.w * i1;
        *(float4*)(ws + OFF_Y0 + (size_t)m * 256 + 4 * fl) = o0;
        *(float4*)(ws + OFF_Y0 + (size_t)m * 256 + 128 + 4 * fl) = o1;
    } else if (b < 1536) {
        const int wid = (b - 1408) * 4 + (t >> 6);
        const int lane = t & 63;
        const int h = wid >> 8, rest = wid & 255;
        const int h0i = rest >> 7;
        const float* wrow = W0 + (size_t)rest * 128;
        float2 w2 = *(const float2*)(wrow + 2 * lane);
        float2 su = *(const float2*)(ws + OFF_U1 + h * 256 + h0i * 128 + 2 * lane);
        float2 sv = *(const float2*)(ws + OFF_V1 + h * 256 + h0i * 128 + 2 * lane);
        float pu = sum64(w2.x * su.x + w2.y * su.y);
        float pv = sum64(w2.x * sv.x + w2.y * sv.y);
        if (lane == 0) { ws[OFF_PP + wid] = pu; ws[OFF_P + wid] = pv; }
    } else {
        // R tiles: 32 blocks of 16-row tiles
        __shared__ float smem[2064];
        const int idx = b - 1536;
        const int h = idx >> 4;
        const int h0i = (idx >> 3) & 1;
        const int f0 = (idx & 7) * 16;
        const float* W0h = W0 + (size_t)h0i * 16384;
        for (int ii = t * 4; ii < 16 * 128; ii += 1024) {
            int i = ii >> 7, d = ii & 127;
            float4 g4 = *(const float4*)(W0h + (size_t)(f0 + i) * 128 + d);
            smem[i * 129 + d + 0] = g4.x;
            smem[i * 129 + d + 1] = g4.y;
            smem[i * 129 + d + 2] = g4.z;
            smem[i * 129 + d + 3] = g4.w;
        }
        __syncthreads();
        const int dg = t & 31, rg = t >> 5;
        float4 acc[2];
        acc[0] = make_float4(0.f, 0.f, 0.f, 0.f);
        acc[1] = make_float4(0.f, 0.f, 0.f, 0.f);
        const float* Qp = ws + OFF_Q + (size_t)h * 32768 + (size_t)h0i * 16384 + 4 * dg;
        #pragma unroll 4
        for (int d = 0; d < 128; ++d) {
            float4 q4 = *(const float4*)(Qp + (size_t)d * 128);
            #pragma unroll
            for (int j = 0; j < 2; ++j) {
                float x = smem[(rg * 2 + j) * 129 + d];
                acc[j].x += x * q4.x; acc[j].y += x * q4.y;
                acc[j].z += x * q4.z; acc[j].w += x * q4.w;
            }
        }
        float* Rp = ws + OFF_R + (size_t)h * 32768 + (size_t)h0i * 16384;
        #pragma unroll
        for (int j = 0; j < 2; ++j)
            *(float4*)(Rp + (size_t)(f0 + rg * 2 + j) * 128 + 4 * dg) = acc[j];
    }
}

// ============ FINAL: 512 threads/block (8 waves); coalesced float2 GEMV ============
__global__ __launch_bounds__(512)
void final_kernel(const float* __restrict__ ws, float* __restrict__ out) {
    __shared__ float xn[22 * 256];
    __shared__ float yb[1024];
    __shared__ float pr[8][2][128];
    __shared__ float en[2][11][2];
    __shared__ float al[2][10][2];
    const int t = threadIdx.x;
    const int m0 = blockIdx.x * 2;
    const int rlane = t & 63;
    const int rg = t >> 6;
    const float* P  = ws + OFF_P;
    const float* Pp = ws + OFF_PP;
    const float* Y1 = ws + OFF_Y1;
    const float* Y0 = ws + OFF_Y0;
    const float4 su0 = *(const float4*)(Pp + 0 + 4 * rlane);
    const float4 su1 = *(const float4*)(Pp + 256 + 4 * rlane);
    const float4 nv0 = *(const float4*)(P + 0 + 4 * rlane);
    const float4 nv1 = *(const float4*)(P + 256 + 4 * rlane);
    float4 g[3];
    #pragma unroll
    for (int i = 0; i < 3; ++i) {
        int rho = rg + 8 * i;
        if (rho < 22) {
            int r = rho / 11, k = rho % 11;
            int m = m0 + r;
            const float* src = (k < 10) ? (Y1 + ((size_t)m * 10 + k) * 256)
                                        : (Y0 + (size_t)m * 256);
            g[i] = *(const float4*)(src + 4 * rlane);
        }
    }
    #pragma unroll
    for (int i = 0; i < 3; ++i) {
        int rho = rg + 8 * i;
        if (rho < 22) {
            int r = rho / 11, k = rho % 11;
            *(float4*)(&xn[rho * 256 + 4 * rlane]) = g[i];
            float p0 = sum64(dot4(g[i], (k < 10) ? nv0 : su0));
            float p1 = sum64(dot4(g[i], (k < 10) ? nv1 : su1));
            if (rlane == 0) { en[r][k][0] = p0; en[r][k][1] = p1; }
        }
    }
    __syncthreads();
    if (t < 128) {
        int r = t >> 6, h = (t >> 5) & 1, k = t & 31;
        float e = -1e30f;
        if (k < 10) {
            float z = en[r][10][h] + en[r][k][h];
            e = (z >= 0.f) ? z : LRELU_SLOPE * z;
        }
        float mx = e;
        #pragma unroll
        for (int off = 16; off > 0; off >>= 1) mx = fmaxf(mx, __shfl_xor(mx, off));
        float ex = (k < 10) ? __expf(e - mx) : 0.f;
        float sm = ex;
        #pragma unroll
        for (int off = 16; off > 0; off >>= 1) sm += __shfl_xor(sm, off);
        if (k < 10) al[r][k][h] = ex / sm;
    }
    __syncthreads();
    #pragma unroll
    for (int i = 0; i < 2; ++i) {
        int c = t + 512 * i;
        int r = c >> 9, rem = c & 511, h = rem >> 8, f = rem & 255;
        float acc = 0.f;
        #pragma unroll
        for (int k = 0; k < 10; ++k) acc += al[r][k][h] * xn[(r * 11 + k) * 256 + f];
        yb[c] = acc;
    }
    __syncthreads();
    {
        const int seg = t >> 6;
        const int op = (t & 63) * 2;
        const float* Rv = ws + OFF_R + (size_t)seg * 64 * 128 + op;
        const float* y0p = yb + seg * 64;
        const float* y1p = yb + 512 + seg * 64;
        float2 a0 = make_float2(0.f, 0.f), a1 = make_float2(0.f, 0.f);
        #pragma unroll 8
        for (int gi = 0; gi < 64; ++gi) {
            float2 rv = *(const float2*)(Rv + (size_t)gi * 128);
            float ya = y0p[gi], yc = y1p[gi];
            a0.x += ya * rv.x; a0.y += ya * rv.y;
            a1.x += yc * rv.x; a1.y += yc * rv.y;
        }
        pr[seg][0][op] = a0.x; pr[seg][0][op + 1] = a0.y;
        pr[seg][1][op] = a1.x; pr[seg][1][op + 1] = a1.y;
    }
    __syncthreads();
    if (t < 256) {
        const int r = t >> 7, o = t & 127;
        float acc = 0.f;
        #pragma unroll
        for (int s = 0; s < 8; ++s) acc += pr[s][r][o];
        out[(size_t)(m0 + r) * 128 + o] = acc;
    }
}

extern "C" void kernel_launch(void* const* d_in, const int* in_sizes, int n_in,
                              void* d_out, int out_size, void* d_ws, size_t ws_size,
                              hipStream_t stream) {
    const float* h0  = (const float*)d_in[0];
    const float* h1  = (const float*)d_in[1];
    const float* h2  = (const float*)d_in[2];
    const float* W0  = (const float*)d_in[3];
    const float* as0 = (const float*)d_in[4];
    const float* an0 = (const float*)d_in[5];
    const float* W1  = (const float*)d_in[6];
    const float* as1 = (const float*)d_in[7];
    const float* an1 = (const float*)d_in[8];
    const float* fcW = (const float*)d_in[9];
    float* outp = (float*)d_out;
    float* ws = (float*)d_ws;

    hipLaunchKernelGGL(prepA_kernel, dim3(224), dim3(256), 0, stream,
                       W0, as0, an0, W1, as1, an1, fcW, ws);
    hipLaunchKernelGGL(big6_kernel, dim3(1568), dim3(256), 0, stream,
                       h0, h1, h2, W0, ws);
    hipLaunchKernelGGL(final_kernel, dim3(512), dim3(512), 0, stream,
                       ws, outp);
}

// Round 18
// 58.705 us; speedup vs baseline: 1.0978x; 1.0068x over previous
//
#include <hip/hip_runtime.h>

#define LRELU_SLOPE 0.2f

// ---------------- workspace layout (float offsets) ----------------
#define OFF_UV0  0u
#define OFF_U1   512u
#define OFF_V1   1024u
#define OFF_P    1536u
#define OFF_PP   2048u
#define OFF_Q    4096u
#define OFF_R    69632u
#define OFF_Y1   135168u
#define OFF_Y0   2756608u

__device__ __forceinline__ float dot4(float4 a, float4 b) {
    return a.x * b.x + a.y * b.y + a.z * b.z + a.w * b.w;
}

template<int CTRL>
__device__ __forceinline__ float dppmov(float x) {
    return __int_as_float(__builtin_amdgcn_update_dpp(
        0, __float_as_int(x), CTRL, 0xf, 0xf, true));
}
__device__ __forceinline__ float sum16(float x) {
    x += dppmov<0xB1>(x);
    x += dppmov<0x4E>(x);
    x += dppmov<0x141>(x);
    x += dppmov<0x140>(x);
    return x;
}
__device__ __forceinline__ float sum32(float x) {
    x = sum16(x);
    return x + __shfl_xor(x, 16);
}
__device__ __forceinline__ float sum64(float x) {
    float y = sum32(x);
    return y + __shfl_xor(y, 32);
}
__device__ __forceinline__ float lrelu(float x) {
    return (x >= 0.f) ? x : LRELU_SLOPE * x;
}

// ============ prepA: uv0, u1/v1, Q = W1 @ fcW-block (unchanged R16) ============
__global__ __launch_bounds__(256)
void prepA_kernel(const float* __restrict__ W0, const float* __restrict__ as0,
                  const float* __restrict__ an0,
                  const float* __restrict__ W1, const float* __restrict__ as1,
                  const float* __restrict__ an1,
                  const float* __restrict__ fcW, float* __restrict__ ws) {
    __shared__ float s[16 * 129];
    const int b = blockIdx.x;
    const int t = threadIdx.x;
    if (b < 192) {
        const int wid = b * 4 + (t >> 6);
        const int lane = t & 63;
        const float *wrow, *as, *an;
        if (wid < 256) {
            wrow = W0 + (size_t)wid * 128;
            int h = wid >> 7;
            as = as0 + h * 128; an = an0 + h * 128;
        } else {
            int g = wid - 256;
            wrow = W1 + (size_t)g * 128;
            int h = g >> 8;
            as = as1 + h * 128; an = an1 + h * 128;
        }
        float2 w = *(const float2*)(wrow + 2 * lane);
        float2 sv = *(const float2*)(as + 2 * lane);
        float2 nv = *(const float2*)(an + 2 * lane);
        float au = sum64(w.x * sv.x + w.y * sv.y);
        float av = sum64(w.x * nv.x + w.y * nv.y);
        if (lane == 0) {
            if (wid < 256) { ws[OFF_UV0 + wid] = au; ws[OFF_UV0 + 256 + wid] = av; }
            else { int g = wid - 256; ws[OFF_U1 + g] = au; ws[OFF_V1 + g] = av; }
        }
    } else {
        const int idx = b - 192;
        const int h = idx >> 4, g0 = (idx & 15) * 16;
        const float* Wh = W1 + (size_t)h * 32768;
        for (int ii = t * 4; ii < 16 * 128; ii += 1024) {
            int i = ii >> 7, d = ii & 127;
            float4 g4 = *(const float4*)(Wh + (size_t)(g0 + i) * 128 + d);
            s[i * 129 + d + 0] = g4.x;
            s[i * 129 + d + 1] = g4.y;
            s[i * 129 + d + 2] = g4.z;
            s[i * 129 + d + 3] = g4.w;
        }
        __syncthreads();
        const int dg = t & 31, rg = t >> 5;
        float4 acc[2];
        acc[0] = make_float4(0.f, 0.f, 0.f, 0.f);
        acc[1] = make_float4(0.f, 0.f, 0.f, 0.f);
        const float* fp = fcW + (size_t)h * 16384 + 4 * dg;
        #pragma unroll 4
        for (int d2 = 0; d2 < 128; ++d2) {
            float4 f4 = *(const float4*)(fp + (size_t)d2 * 128);
            #pragma unroll
            for (int j = 0; j < 2; ++j) {
                float x = s[(rg * 2 + j) * 129 + d2];
                acc[j].x += x * f4.x; acc[j].y += x * f4.y;
                acc[j].z += x * f4.z; acc[j].w += x * f4.w;
            }
        }
        float* Qp = ws + OFF_Q + (size_t)h * 32768;
        #pragma unroll
        for (int j = 0; j < 2; ++j)
            *(float4*)(Qp + (size_t)(g0 + rg * 2 + j) * 128 + 4 * dg) = acc[j];
    }
}

// online-softmax updates
__device__ __forceinline__ void upd2(float& m, float& s, float4& A,
                                     float ea, float eb,
                                     const float4& xa, const float4& xb) {
    float mn = fmaxf(m, fmaxf(ea, eb));
    float sc = __expf(m - mn);
    float pa = __expf(ea - mn);
    float pb = __expf(eb - mn);
    s = s * sc + pa + pb;
    A.x = A.x * sc + pa * xa.x + pb * xb.x;
    A.y = A.y * sc + pa * xa.y + pb * xb.y;
    A.z = A.z * sc + pa * xa.z + pb * xb.z;
    A.w = A.w * sc + pa * xa.w + pb * xb.w;
    m = mn;
}
__device__ __forceinline__ void upd1(float& m, float& s, float4& A,
                                     float ea, const float4& xa) {
    float mn = fmaxf(m, ea);
    float sc = __expf(m - mn);
    float pa = __expf(ea - mn);
    s = s * sc + pa;
    A.x = A.x * sc + pa * xa.x;
    A.y = A.y * sc + pa * xa.y;
    A.z = A.z * sc + pa * xa.z;
    A.w = A.w * sc + pa * xa.w;
    m = mn;
}

// ============ big6: 2 targets/wave, DEPTH-4 row prefetch (unchanged R16) ============
__global__ __launch_bounds__(256)
void big6_kernel(const float* __restrict__ h0, const float* __restrict__ h1,
                 const float* __restrict__ h2, const float* __restrict__ W0,
                 float* __restrict__ ws) {
    const int b = blockIdx.x;
    const int t = threadIdx.x;
    const float* uv0 = ws + OFF_UV0;

    if (b < 1280) {
        const int lane = t & 63;
        const int sub = lane >> 5;
        const int fl = lane & 31;
        const int m = (b * 4 + (t >> 6)) * 2 + sub;
        const float* xnp = h2 + (size_t)m * 3200;
        float es0, es1;
        {
            const float4 xs = *(const float4*)(h1 + (size_t)m * 128 + 4 * fl);
            const float4 u0 = *(const float4*)(uv0 + 0 + 4 * fl);
            const float4 u1 = *(const float4*)(uv0 + 128 + 4 * fl);
            es0 = sum32(dot4(xs, u0));
            es1 = sum32(dot4(xs, u1));
        }
        const float4 v0 = *(const float4*)(uv0 + 256 + 4 * fl);
        const float4 v1 = *(const float4*)(uv0 + 384 + 4 * fl);

        float4 xa = *(const float4*)(xnp + 4 * fl);
        float4 xb = *(const float4*)(xnp + 128 + 4 * fl);
        float4 xc = *(const float4*)(xnp + 256 + 4 * fl);
        float4 xd = *(const float4*)(xnp + 384 + 4 * fl);
        float m0 = -1e30f, m1 = -1e30f, s0 = 0.f, s1 = 0.f;
        float4 A0 = make_float4(0.f, 0.f, 0.f, 0.f);
        float4 A1 = make_float4(0.f, 0.f, 0.f, 0.f);
        #pragma unroll
        for (int c = 0; c < 12; ++c) {
            float4 na, nb;
            if (c < 10) {
                na = *(const float4*)(xnp + (size_t)(2 * c + 4) * 128 + 4 * fl);
                nb = *(const float4*)(xnp + (size_t)(2 * c + 5) * 128 + 4 * fl);
            } else if (c == 10) {
                na = *(const float4*)(xnp + (size_t)24 * 128 + 4 * fl);
                nb = na;
            } else {
                na = xc; nb = xd;
            }
            float ea0 = lrelu(es0 + sum32(dot4(xa, v0)));
            float ea1 = lrelu(es1 + sum32(dot4(xa, v1)));
            float eb0 = lrelu(es0 + sum32(dot4(xb, v0)));
            float eb1 = lrelu(es1 + sum32(dot4(xb, v1)));
            upd2(m0, s0, A0, ea0, eb0, xa, xb);
            upd2(m1, s1, A1, ea1, eb1, xa, xb);
            xa = xc; xb = xd; xc = na; xd = nb;
        }
        {
            float e0 = lrelu(es0 + sum32(dot4(xa, v0)));
            float e1 = lrelu(es1 + sum32(dot4(xa, v1)));
            upd1(m0, s0, A0, e0, xa);
            upd1(m1, s1, A1, e1, xa);
        }
        const float i0 = 1.f / s0, i1 = 1.f / s1;
        float4 o0, o1;
        o0.x = A0.x * i0; o0.y = A0.y * i0; o0.z = A0.z * i0; o0.w = A0.w * i0;
        o1.x = A1.x * i1; o1.y = A1.y * i1; o1.z = A1.z * i1; o1.w = A1.w * i1;
        *(float4*)(ws + OFF_Y1 + (size_t)m * 256 + 4 * fl) = o0;
        *(float4*)(ws + OFF_Y1 + (size_t)m * 256 + 128 + 4 * fl) = o1;
    } else if (b < 1408) {
        const int lane = t & 63;
        const int sub = lane >> 5;
        const int fl = lane & 31;
        const int m = ((b - 1280) * 4 + (t >> 6)) * 2 + sub;
        const float* xnp = h1 + (size_t)m * 1280;
        float es0, es1;
        {
            const float4 xs = *(const float4*)(h0 + (size_t)m * 128 + 4 * fl);
            const float4 u0 = *(const float4*)(uv0 + 0 + 4 * fl);
            const float4 u1 = *(const float4*)(uv0 + 128 + 4 * fl);
            es0 = sum32(dot4(xs, u0));
            es1 = sum32(dot4(xs, u1));
        }
        const float4 v0 = *(const float4*)(uv0 + 256 + 4 * fl);
        const float4 v1 = *(const float4*)(uv0 + 384 + 4 * fl);

        float4 xa = *(const float4*)(xnp + 4 * fl);
        float4 xb = *(const float4*)(xnp + 128 + 4 * fl);
        float4 xc = *(const float4*)(xnp + 256 + 4 * fl);
        float4 xd = *(const float4*)(xnp + 384 + 4 * fl);
        float m0 = -1e30f, m1 = -1e30f, s0 = 0.f, s1 = 0.f;
        float4 A0 = make_float4(0.f, 0.f, 0.f, 0.f);
        float4 A1 = make_float4(0.f, 0.f, 0.f, 0.f);
        #pragma unroll
        for (int c = 0; c < 5; ++c) {
            float4 na, nb;
            if (c < 3) {
                na = *(const float4*)(xnp + (size_t)(2 * c + 4) * 128 + 4 * fl);
                nb = *(const float4*)(xnp + (size_t)(2 * c + 5) * 128 + 4 * fl);
            } else {
                na = xc; nb = xd;
            }
            float ea0 = lrelu(es0 + sum32(dot4(xa, v0)));
            float ea1 = lrelu(es1 + sum32(dot4(xa, v1)));
            float eb0 = lrelu(es0 + sum32(dot4(xb, v0)));
            float eb1 = lrelu(es1 + sum32(dot4(xb, v1)));
            upd2(m0, s0, A0, ea0, eb0, xa, xb);
            upd2(m1, s1, A1, ea1, eb1, xa, xb);
            xa = xc; xb = xd; xc = na; xd = nb;
        }
        const float i0 = 1.f / s0, i1 = 1.f / s1;
        float4 o0, o1;
        o0.x = A0.x * i0; o0.y = A0.y * i0; o0.z = A0.z * i0; o0.w = A0.w * i0;
        o1.x = A1.x * i1; o1.y = A1.y * i1; o1.z = A1.z * i1; o1.w = A1.w * i1;
        *(float4*)(ws + OFF_Y0 + (size_t)m * 256 + 4 * fl) = o0;
        *(float4*)(ws + OFF_Y0 + (size_t)m * 256 + 128 + 4 * fl) = o1;
    } else if (b < 1536) {
        const int wid = (b - 1408) * 4 + (t >> 6);
        const int lane = t & 63;
        const int h = wid >> 8, rest = wid & 255;
        const int h0i = rest >> 7;
        const float* wrow = W0 + (size_t)rest * 128;
        float2 w2 = *(const float2*)(wrow + 2 * lane);
        float2 su = *(const float2*)(ws + OFF_U1 + h * 256 + h0i * 128 + 2 * lane);
        float2 sv = *(const float2*)(ws + OFF_V1 + h * 256 + h0i * 128 + 2 * lane);
        float pu = sum64(w2.x * su.x + w2.y * su.y);
        float pv = sum64(w2.x * sv.x + w2.y * sv.y);
        if (lane == 0) { ws[OFF_PP + wid] = pu; ws[OFF_P + wid] = pv; }
    } else {
        __shared__ float smem[2064];
        const int idx = b - 1536;
        const int h = idx >> 4;
        const int h0i = (idx >> 3) & 1;
        const int f0 = (idx & 7) * 16;
        const float* W0h = W0 + (size_t)h0i * 16384;
        for (int ii = t * 4; ii < 16 * 128; ii += 1024) {
            int i = ii >> 7, d = ii & 127;
            float4 g4 = *(const float4*)(W0h + (size_t)(f0 + i) * 128 + d);
            smem[i * 129 + d + 0] = g4.x;
            smem[i * 129 + d + 1] = g4.y;
            smem[i * 129 + d + 2] = g4.z;
            smem[i * 129 + d + 3] = g4.w;
        }
        __syncthreads();
        const int dg = t & 31, rg = t >> 5;
        float4 acc[2];
        acc[0] = make_float4(0.f, 0.f, 0.f, 0.f);
        acc[1] = make_float4(0.f, 0.f, 0.f, 0.f);
        const float* Qp = ws + OFF_Q + (size_t)h * 32768 + (size_t)h0i * 16384 + 4 * dg;
        #pragma unroll 4
        for (int d = 0; d < 128; ++d) {
            float4 q4 = *(const float4*)(Qp + (size_t)d * 128);
            #pragma unroll
            for (int j = 0; j < 2; ++j) {
                float x = smem[(rg * 2 + j) * 129 + d];
                acc[j].x += x * q4.x; acc[j].y += x * q4.y;
                acc[j].z += x * q4.z; acc[j].w += x * q4.w;
            }
        }
        float* Rp = ws + OFF_R + (size_t)h * 32768 + (size_t)h0i * 16384;
        #pragma unroll
        for (int j = 0; j < 2; ++j)
            *(float4*)(Rp + (size_t)(f0 + rg * 2 + j) * 128 + 4 * dg) = acc[j];
    }
}

// ============ FINAL4: 4 targets/block, NO xn staging (rows re-read from L2) ============
// 256 blocks x 512 threads. R read once per 4 targets (67 MB total vs 134).
__global__ __launch_bounds__(512)
void final4_kernel(const float* __restrict__ ws, float* __restrict__ out) {
    __shared__ float yb[2048];            // [r][h*256+f]
    __shared__ float pr[8][4][128];       // GEMV partials
    __shared__ float en[4][11][2];
    __shared__ float al[4][10][2];
    const int t = threadIdx.x;
    const int m0 = blockIdx.x * 4;
    const int rlane = t & 63;
    const int rg = t >> 6;                // 8 waves
    const float* P  = ws + OFF_P;
    const float* Pp = ws + OFF_PP;
    const float* Y1 = ws + OFF_Y1;
    const float* Y0 = ws + OFF_Y0;
    const float4 su0 = *(const float4*)(Pp + 0 + 4 * rlane);
    const float4 su1 = *(const float4*)(Pp + 256 + 4 * rlane);
    const float4 nv0 = *(const float4*)(P + 0 + 4 * rlane);
    const float4 nv1 = *(const float4*)(P + 256 + 4 * rlane);

    // phase 1: logits for 44 rows (4 targets x 11); rows read once, discarded
    #pragma unroll
    for (int i = 0; i < 6; ++i) {
        int rho = rg + 8 * i;
        if (rho < 44) {
            int r = rho / 11, k = rho % 11;
            int m = m0 + r;
            const float* src = (k < 10) ? (Y1 + ((size_t)m * 10 + k) * 256)
                                        : (Y0 + (size_t)m * 256);
            float4 g = *(const float4*)(src + 4 * rlane);
            float p0 = sum64(dot4(g, (k < 10) ? nv0 : su0));
            float p1 = sum64(dot4(g, (k < 10) ? nv1 : su1));
            if (rlane == 0) { en[r][k][0] = p0; en[r][k][1] = p1; }
        }
    }
    __syncthreads();
    // phase 2: softmax over K=10 for 4 targets x 2 heads
    if (t < 256) {
        int r = t >> 6, h = (t >> 5) & 1, k = t & 31;
        float e = -1e30f;
        if (k < 10) {
            float z = en[r][10][h] + en[r][k][h];
            e = (z >= 0.f) ? z : LRELU_SLOPE * z;
        }
        float mx = e;
        #pragma unroll
        for (int off = 16; off > 0; off >>= 1) mx = fmaxf(mx, __shfl_xor(mx, off));
        float ex = (k < 10) ? __expf(e - mx) : 0.f;
        float sm = ex;
        #pragma unroll
        for (int off = 16; off > 0; off >>= 1) sm += __shfl_xor(sm, off);
        if (k < 10) al[r][k][h] = ex / sm;
    }
    __syncthreads();
    // phase 3: ybar — SAME 256-float row for both heads (index by f, NOT rem!)
    #pragma unroll
    for (int i = 0; i < 4; ++i) {
        int c = t + 512 * i;              // [0,2048)
        int r = c >> 9, rem = c & 511, h = rem >> 8, f = rem & 255;
        const float* base = Y1 + ((size_t)(m0 + r) * 10) * 256 + f;
        float acc = 0.f;
        #pragma unroll
        for (int k = 0; k < 10; ++k) acc += al[r][k][h] * base[k * 256];
        yb[c] = acc;
    }
    __syncthreads();
    // phase 4: GEMV out[m0+r][o] = sum_gi yb[r*512+gi] * R[gi][o]; R read ONCE
    {
        const int seg = t >> 6;           // 8 gi-segments of 64
        const int op = (t & 63) * 2;
        const float* Rv = ws + OFF_R + (size_t)seg * 64 * 128 + op;
        float2 a[4];
        #pragma unroll
        for (int r = 0; r < 4; ++r) a[r] = make_float2(0.f, 0.f);
        #pragma unroll 4
        for (int gi = 0; gi < 64; ++gi) {
            float2 rv = *(const float2*)(Rv + (size_t)gi * 128);
            #pragma unroll
            for (int r = 0; r < 4; ++r) {
                float yv = yb[r * 512 + seg * 64 + gi];
                a[r].x += yv * rv.x;
                a[r].y += yv * rv.y;
            }
        }
        #pragma unroll
        for (int r = 0; r < 4; ++r) {
            pr[seg][r][op] = a[r].x;
            pr[seg][r][op + 1] = a[r].y;
        }
    }
    __syncthreads();
    {
        const int r = t >> 7, o = t & 127;   // 512 threads = 4 x 128
        float acc = 0.f;
        #pragma unroll
        for (int s = 0; s < 8; ++s) acc += pr[s][r][o];
        out[(size_t)(m0 + r) * 128 + o] = acc;
    }
}

extern "C" void kernel_launch(void* const* d_in, const int* in_sizes, int n_in,
                              void* d_out, int out_size, void* d_ws, size_t ws_size,
                              hipStream_t stream) {
    const float* h0  = (const float*)d_in[0];
    const float* h1  = (const float*)d_in[1];
    const float* h2  = (const float*)d_in[2];
    const float* W0  = (const float*)d_in[3];
    const float* as0 = (const float*)d_in[4];
    const float* an0 = (const float*)d_in[5];
    const float* W1  = (const float*)d_in[6];
    const float* as1 = (const float*)d_in[7];
    const float* an1 = (const float*)d_in[8];
    const float* fcW = (const float*)d_in[9];
    float* outp = (float*)d_out;
    float* ws = (float*)d_ws;

    hipLaunchKernelGGL(prepA_kernel, dim3(224), dim3(256), 0, stream,
                       W0, as0, an0, W1, as1, an1, fcW, ws);
    hipLaunchKernelGGL(big6_kernel, dim3(1568), dim3(256), 0, stream,
                       h0, h1, h2, W0, ws);
    hipLaunchKernelGGL(final4_kernel, dim3(256), dim3(512), 0, stream,
                       ws, outp);
}